// Round 3
// baseline (454.696 us; speedup 1.0000x reference)
//
#include <hip/hip_runtime.h>

typedef unsigned short u16;
typedef short bf16x8 __attribute__((ext_vector_type(8)));
typedef float f32x4 __attribute__((ext_vector_type(4)));

#define D_IN 2048
#define H_DIM 2048
#define K_CH 4096

__device__ __forceinline__ u16 f2bf(float f) {
  unsigned int u = __float_as_uint(f);
  u += 0x7fffu + ((u >> 16) & 1u);   // round-to-nearest-even
  return (u16)(u >> 16);
}
__device__ __forceinline__ float sigmoidf(float x) {
  return 1.0f / (1.0f + __expf(-x));
}
__device__ __forceinline__ uint4 packrow(float4 a, float4 b) {
  uint4 w;
  w.x = (unsigned)f2bf(a.x) | ((unsigned)f2bf(a.y) << 16);
  w.y = (unsigned)f2bf(a.z) | ((unsigned)f2bf(a.w) << 16);
  w.z = (unsigned)f2bf(b.x) | ((unsigned)f2bf(b.y) << 16);
  w.w = (unsigned)f2bf(b.z) | ((unsigned)f2bf(b.w) << 16);
  return w;
}

// ---------------------------------------------------------------------------
// K1 (fused prep, 3585 blocks, all roles LDS-free / high occupancy):
//  [0,1024):    4 rows of children_h: column-sum partials + bf16 convert
//  [1024,1536): wfhb = bf16(W_fh), 8192 elems/block
//  [1536,2048): g[h] = W_fx[h]·x + b_fx + b_fh    (1 wave/row)
//  [2048,3584): ioux[row] = W_iou_x[row]·x + b_iou_x + b_iou_h (1 wave/row)
//  3584:        zero hsum[2048] + accv[2048] + ticket[256]
// ---------------------------------------------------------------------------
__global__ __launch_bounds__(256) void k1(
    const float* __restrict__ ch, const float* __restrict__ wfh,
    const float* __restrict__ Wfx, const float* __restrict__ bfx,
    const float* __restrict__ bfh, const float* __restrict__ x,
    const float* __restrict__ Wix, const float* __restrict__ bix,
    const float* __restrict__ bih, float* __restrict__ partials,
    u16* __restrict__ chb, u16* __restrict__ wfhb, float* __restrict__ g,
    float* __restrict__ ioux, float* __restrict__ hsum,
    float* __restrict__ accv, float* __restrict__ ticket) {
  const int t = threadIdx.x;
  const int bid = blockIdx.x;
  if (bid < 1024) {
    const int r0 = bid * 4;
    float4 a[4], b[4];
#pragma unroll
    for (int r = 0; r < 4; ++r) {
      const float4* p = (const float4*)(ch + (size_t)(r0 + r) * H_DIM + t * 8);
      a[r] = p[0];
      b[r] = p[1];
    }
    float s0 = 0.f, s1 = 0.f, s2 = 0.f, s3 = 0.f;
    float s4 = 0.f, s5 = 0.f, s6 = 0.f, s7 = 0.f;
#pragma unroll
    for (int r = 0; r < 4; ++r) {
      s0 += a[r].x; s1 += a[r].y; s2 += a[r].z; s3 += a[r].w;
      s4 += b[r].x; s5 += b[r].y; s6 += b[r].z; s7 += b[r].w;
      *(uint4*)(chb + (size_t)(r0 + r) * H_DIM + t * 8) = packrow(a[r], b[r]);
    }
    float4 lo, hi;
    lo.x = s0; lo.y = s1; lo.z = s2; lo.w = s3;
    hi.x = s4; hi.y = s5; hi.z = s6; hi.w = s7;
    float* pp = partials + (size_t)bid * H_DIM + t * 8;
    *(float4*)pp = lo;
    *(float4*)(pp + 4) = hi;
  } else if (bid < 1536) {
    const size_t base = (size_t)(bid - 1024) * 8192 + t * 8;
    float4 a[4], b[4];
#pragma unroll
    for (int j = 0; j < 4; ++j) {
      const float4* p = (const float4*)(wfh + base + j * 2048);
      a[j] = p[0];
      b[j] = p[1];
    }
#pragma unroll
    for (int j = 0; j < 4; ++j)
      *(uint4*)(wfhb + base + j * 2048) = packrow(a[j], b[j]);
  } else if (bid < 2048) {
    const int wave = t >> 6, lane = t & 63;
    const int h = (bid - 1536) * 4 + wave;  // 0..2047
    const float4* w = (const float4*)(Wfx + (size_t)h * D_IN);
    const float4* xv = (const float4*)x;
    float s = 0.f;
#pragma unroll
    for (int i = 0; i < 8; ++i) {
      int idx = i * 64 + lane;
      float4 av = w[idx], bv = xv[idx];
      s += av.x * bv.x + av.y * bv.y + av.z * bv.z + av.w * bv.w;
    }
#pragma unroll
    for (int off = 32; off > 0; off >>= 1) s += __shfl_xor(s, off);
    if (lane == 0) g[h] = s + bfx[h] + bfh[h];
  } else if (bid < 3584) {
    const int wave = t >> 6, lane = t & 63;
    const int row = (bid - 2048) * 4 + wave;  // 0..6143
    const float4* w = (const float4*)(Wix + (size_t)row * D_IN);
    const float4* xv = (const float4*)x;
    float s = 0.f;
#pragma unroll
    for (int i = 0; i < 8; ++i) {
      int idx = i * 64 + lane;
      float4 av = w[idx], bv = xv[idx];
      s += av.x * bv.x + av.y * bv.y + av.z * bv.z + av.w * bv.w;
    }
#pragma unroll
    for (int off = 32; off > 0; off >>= 1) s += __shfl_xor(s, off);
    if (lane == 0) ioux[row] = s + bix[row] + bih[row];
  } else {
    float4 z = {0.f, 0.f, 0.f, 0.f};
    ((float4*)hsum)[t * 2] = z;
    ((float4*)hsum)[t * 2 + 1] = z;
    ((float4*)accv)[t * 2] = z;
    ((float4*)accv)[t * 2 + 1] = z;
    if (t < 64) ((float4*)ticket)[t] = z;
  }
}

// ---------------------------------------------------------------------------
// kG (320 blocks, 512 threads):
//  [0,64):   hsum reduction over partials (kred role; retires in ~5us, so the
//            64 late GEMM blocks start only ~5us behind the first 192).
//  [64,320): bf16 GEMM + sigmoid + weighted K-reduction.
//            Tile 256x128 (BM children-dim, BN H-dim), BK=64, 8 waves (4m x
//            2n), LDS 96 KiB (1 block/CU, 8 waves/CU), 2-phase dbuf.
//            XCD-grouped swizzle: XCD x owns bm in {2x,2x+1} x all 16 bn, so
//            co-resident blocks on an XCD share K-slices in its L2 (live set
//            ~320 KB << 4 MiB) instead of re-fetching 384 MB from L3.
// ---------------------------------------------------------------------------
#define BM 256
#define BN 128
#define BK 64

__global__ __launch_bounds__(512) void kG(
    const u16* __restrict__ chb, const float* __restrict__ cc,
    const u16* __restrict__ wfhb, const float* __restrict__ g,
    const float* __restrict__ partials, float* __restrict__ hsum,
    float* __restrict__ accv) {
  __shared__ u16 As[2][BM * BK];  // 64 KiB; row stride 64 u16 (128 B)
  __shared__ u16 Bs[2][BN * BK];  // 32 KiB

  const int bid = blockIdx.x;
  const int t = threadIdx.x;

  if (bid < 64) {
    // --- kred role: 512 threads = 256 cols x 2 row-halves ---
    const int c = (bid & 7) * 256 + (t & 255);
    const int p0 = (bid >> 3) * 128 + (t >> 8) * 64;
    float a0 = 0.f, a1 = 0.f, a2 = 0.f, a3 = 0.f;
    float a4 = 0.f, a5 = 0.f, a6 = 0.f, a7 = 0.f;
    for (int p = p0; p < p0 + 64; p += 8) {
      a0 += partials[(size_t)(p + 0) * H_DIM + c];
      a1 += partials[(size_t)(p + 1) * H_DIM + c];
      a2 += partials[(size_t)(p + 2) * H_DIM + c];
      a3 += partials[(size_t)(p + 3) * H_DIM + c];
      a4 += partials[(size_t)(p + 4) * H_DIM + c];
      a5 += partials[(size_t)(p + 5) * H_DIM + c];
      a6 += partials[(size_t)(p + 6) * H_DIM + c];
      a7 += partials[(size_t)(p + 7) * H_DIM + c];
    }
    float s = ((a0 + a1) + (a2 + a3)) + ((a4 + a5) + (a6 + a7));
    atomicAdd(hsum + c, s);
    return;
  }

  // --- GEMM role ---
  const int gb = bid - 64;                 // 0..255; gb%8 == bid%8 -> XCD id
  const int xcd = gb & 7;
  const int u = gb >> 3;                   // 0..31
  const int bm = (xcd << 1) | (u >> 4);    // 0..15
  const int bn = u & 15;                   // 0..15
  const int row0 = bm * BM;
  const int col0 = bn * BN;

  const int wave = t >> 6, lane = t & 63;
  const int lrow = lane & 15, lquad = lane >> 4;
  const int wm = wave >> 1, wn = wave & 1; // 4m x 2n -> per-wave 64x64 out

  f32x4 acc[4][4] = {};

  const int srow = lane >> 3;           // row within the 8-row group
  const int schunk = (lane & 7) ^ srow; // XOR-swizzled source chunk
  const u16* agbase = chb  + (size_t)(row0 + wave * 32 + srow) * H_DIM + schunk * 8;
  const u16* bgbase = wfhb + (size_t)(col0 + wave * 16 + srow) * H_DIM + schunk * 8;

#define STAGE(buf, kb)                                                        \
  do {                                                                        \
    _Pragma("unroll")                                                         \
    for (int i = 0; i < 4; ++i)                                               \
      __builtin_amdgcn_global_load_lds(                                       \
          (const __attribute__((address_space(1))) void*)(agbase + (size_t)i * 8 * H_DIM + (kb) * BK), \
          (__attribute__((address_space(3))) void*)(&As[buf][(wave * 32 + i * 8) * 64]), \
          16, 0, 0);                                                          \
    _Pragma("unroll")                                                         \
    for (int i = 0; i < 2; ++i)                                               \
      __builtin_amdgcn_global_load_lds(                                       \
          (const __attribute__((address_space(1))) void*)(bgbase + (size_t)i * 8 * H_DIM + (kb) * BK), \
          (__attribute__((address_space(3))) void*)(&Bs[buf][(wave * 16 + i * 8) * 64]), \
          16, 0, 0);                                                          \
  } while (0)

#define COMPUTE(buf)                                                          \
  do {                                                                        \
    _Pragma("unroll")                                                         \
    for (int step = 0; step < 2; ++step) {                                    \
      const int slot = ((step * 4 + lquad) ^ (lrow & 7)) * 8;                 \
      bf16x8 fa[4], fb[4];                                                    \
      _Pragma("unroll")                                                       \
      for (int i = 0; i < 4; ++i)                                             \
        fa[i] = *(const bf16x8*)(&As[buf][(wm * 64 + i * 16 + lrow) * 64 + slot]); \
      _Pragma("unroll")                                                       \
      for (int i = 0; i < 4; ++i)                                             \
        fb[i] = *(const bf16x8*)(&Bs[buf][(wn * 64 + i * 16 + lrow) * 64 + slot]); \
      _Pragma("unroll")                                                       \
      for (int mi = 0; mi < 4; ++mi)                                          \
        _Pragma("unroll")                                                     \
        for (int ni = 0; ni < 4; ++ni)                                        \
          acc[mi][ni] = __builtin_amdgcn_mfma_f32_16x16x32_bf16(              \
              fa[mi], fb[ni], acc[mi][ni], 0, 0, 0);                          \
    }                                                                         \
  } while (0)

  // prologue: tile 0 into buf 0
  STAGE(0, 0);
  __syncthreads();  // vmcnt(0) drain -> buf0 ready

  for (int kb = 0; kb < D_IN / BK - 1; ++kb) {
    const int cur = kb & 1;
    STAGE(cur ^ 1, kb + 1);  // issue next-tile loads BEFORE compute
    COMPUTE(cur);
    __syncthreads();         // drains vmcnt(0): buf^1 ready; reads of buf done
  }
  COMPUTE(1);  // tile 31

  // Epilogue. C/D layout: col = lane&15, row = (lane>>4)*4 + reg.
#pragma unroll
  for (int ni = 0; ni < 4; ++ni) {
    const int colg = col0 + wn * 64 + ni * 16 + lrow;
    const float gv = g[colg];
    float s = 0.f;
#pragma unroll
    for (int mi = 0; mi < 4; ++mi) {
      const int rowg = row0 + wm * 64 + mi * 16 + lquad * 4;
#pragma unroll
      for (int r = 0; r < 4; ++r) {
        float f = sigmoidf(gv + acc[mi][ni][r]);
        s += f * cc[(size_t)(rowg + r) * H_DIM + colg];
      }
    }
    s += __shfl_xor(s, 16);
    s += __shfl_xor(s, 32);
    if (lquad == 0) atomicAdd(accv + colg, s);
  }
#undef STAGE
#undef COMPUTE
}

// ---------------------------------------------------------------------------
// kmv3: iou[row] += W_iou_h[row]·hsum, LDS-free / 32 waves-per-CU streaming.
// The LAST block (device-scope ticket) also runs the finalize epilogue
// (replaces the separate kfinal dispatch).
// ---------------------------------------------------------------------------
__global__ __launch_bounds__(256) void kmv3(const float* __restrict__ Wih,
                                            const float* __restrict__ hsum,
                                            float* __restrict__ iou,
                                            const float* __restrict__ accv,
                                            float* __restrict__ ticket,
                                            float* __restrict__ out) {
  const int t = threadIdx.x;
  const int wave = t >> 6, lane = t & 63;
  const int row = blockIdx.x * 4 + wave;  // 0..6143
  const float4* w = (const float4*)(Wih + (size_t)row * H_DIM);
  const float4* hv = (const float4*)hsum;
  float s = 0.f;
#pragma unroll
  for (int i = 0; i < 8; ++i) {
    int idx = i * 64 + lane;
    float4 a = w[idx], b = hv[idx];
    s += a.x * b.x + a.y * b.y + a.z * b.z + a.w * b.w;
  }
#pragma unroll
  for (int off = 32; off > 0; off >>= 1) s += __shfl_xor(s, off);
  if (lane == 0) iou[row] += s;

  // last-block finalize
  __threadfence();
  __syncthreads();
  __shared__ int lastflag;
  if (t == 0) {
    unsigned int v = atomicAdd((unsigned int*)ticket, 1u);
    lastflag = (v == (unsigned int)(gridDim.x - 1));
  }
  __syncthreads();
  if (lastflag) {
    __threadfence();
    for (int h = t; h < H_DIM; h += 256) {
      float si = sigmoidf(iou[h]);
      float so = sigmoidf(iou[H_DIM + h]);
      float tu = tanhf(iou[2 * H_DIM + h]);
      float c = si * tu + accv[h];
      float hh = so * tanhf(c);
      out[h] = so;
      out[H_DIM + h] = c;
      out[2 * H_DIM + h] = hh;
    }
  }
}

extern "C" void kernel_launch(void* const* d_in, const int* in_sizes, int n_in,
                              void* d_out, int out_size, void* d_ws, size_t ws_size,
                              hipStream_t stream) {
  const float* x   = (const float*)d_in[0];   // input [2048]
  const float* cc  = (const float*)d_in[1];   // children_c [4096,2048]
  const float* ch  = (const float*)d_in[2];   // children_h [4096,2048]
  const float* Wix = (const float*)d_in[3];   // W_iou_x [6144,2048]
  const float* bix = (const float*)d_in[4];   // b_iou_x [6144]
  const float* Wih = (const float*)d_in[5];   // W_iou_h [6144,2048]
  const float* bih = (const float*)d_in[6];   // b_iou_h [6144]
  const float* Wfx = (const float*)d_in[7];   // W_fx [2048,2048]
  const float* bfx = (const float*)d_in[8];   // b_fx [2048]
  const float* Wfh = (const float*)d_in[9];   // W_fh [2048,2048]
  const float* bfh = (const float*)d_in[10];  // b_fh [2048]

  float* ws   = (float*)d_ws;
  float* hsum = ws;                    // [2048]  (zeroed in k1; kG atomics)
  float* iou  = ws + 2048;             // [6144]  (ioux by k1; += in kmv3)
  float* g    = ws + 8192;             // [2048]
  float* accv = ws + 10240;            // [2048]  (zeroed in k1; kG atomics)
  float* ticket = ws + 12288;          // [256]   (zeroed in k1; kmv3 ticket)
  float* partials = ws + 12544;        // [1024 * 2048]
  u16* chb  = (u16*)(ws + 12544 + 1024 * 2048);  // [4096*2048] bf16
  u16* wfhb = chb + (size_t)K_CH * H_DIM;        // [2048*2048] bf16
  float* out = (float*)d_out;

  k1<<<3585, 256, 0, stream>>>(ch, Wfh, Wfx, bfx, bfh, x, Wix, bix, bih,
                               partials, chb, wfhb, g, iou, hsum, accv, ticket);
  kG<<<320, 512, 0, stream>>>(chb, cc, wfhb, g, partials, hsum, accv);
  kmv3<<<1536, 256, 0, stream>>>(Wih, hsum, iou, accv, ticket, out);
}

// Round 4
// 256.008 us; speedup vs baseline: 1.7761x; 1.7761x over previous
//
#include <hip/hip_runtime.h>

typedef unsigned short u16;
typedef short bf16x8 __attribute__((ext_vector_type(8)));
typedef float f32x4 __attribute__((ext_vector_type(4)));

#define D_IN 2048
#define H_DIM 2048
#define K_CH 4096

__device__ __forceinline__ u16 f2bf(float f) {
  unsigned int u = __float_as_uint(f);
  u += 0x7fffu + ((u >> 16) & 1u);   // round-to-nearest-even
  return (u16)(u >> 16);
}
__device__ __forceinline__ float sigmoidf(float x) {
  return 1.0f / (1.0f + __expf(-x));
}
__device__ __forceinline__ uint4 packrow(float4 a, float4 b) {
  uint4 w;
  w.x = (unsigned)f2bf(a.x) | ((unsigned)f2bf(a.y) << 16);
  w.y = (unsigned)f2bf(a.z) | ((unsigned)f2bf(a.w) << 16);
  w.z = (unsigned)f2bf(b.x) | ((unsigned)f2bf(b.y) << 16);
  w.w = (unsigned)f2bf(b.z) | ((unsigned)f2bf(b.w) << 16);
  return w;
}

// ---------------------------------------------------------------------------
// K1 (fused prep, 3585 blocks, all roles LDS-free / high occupancy):
//  [0,1024):    4 rows of children_h: column-sum partials + bf16 convert
//  [1024,1536): wfhb = bf16(W_fh), 8192 elems/block
//  [1536,2048): g[h] = W_fx[h]·x + b_fx + b_fh    (1 wave/row)
//  [2048,3584): ioux[row] = W_iou_x[row]·x + b_iou_x + b_iou_h (1 wave/row)
//  3584:        zero hsum[2048] + accv[2048]
// ---------------------------------------------------------------------------
__global__ __launch_bounds__(256) void k1(
    const float* __restrict__ ch, const float* __restrict__ wfh,
    const float* __restrict__ Wfx, const float* __restrict__ bfx,
    const float* __restrict__ bfh, const float* __restrict__ x,
    const float* __restrict__ Wix, const float* __restrict__ bix,
    const float* __restrict__ bih, float* __restrict__ partials,
    u16* __restrict__ chb, u16* __restrict__ wfhb, float* __restrict__ g,
    float* __restrict__ ioux, float* __restrict__ hsum,
    float* __restrict__ accv) {
  const int t = threadIdx.x;
  const int bid = blockIdx.x;
  if (bid < 1024) {
    const int r0 = bid * 4;
    float4 a[4], b[4];
#pragma unroll
    for (int r = 0; r < 4; ++r) {
      const float4* p = (const float4*)(ch + (size_t)(r0 + r) * H_DIM + t * 8);
      a[r] = p[0];
      b[r] = p[1];
    }
    float s0 = 0.f, s1 = 0.f, s2 = 0.f, s3 = 0.f;
    float s4 = 0.f, s5 = 0.f, s6 = 0.f, s7 = 0.f;
#pragma unroll
    for (int r = 0; r < 4; ++r) {
      s0 += a[r].x; s1 += a[r].y; s2 += a[r].z; s3 += a[r].w;
      s4 += b[r].x; s5 += b[r].y; s6 += b[r].z; s7 += b[r].w;
      *(uint4*)(chb + (size_t)(r0 + r) * H_DIM + t * 8) = packrow(a[r], b[r]);
    }
    float4 lo, hi;
    lo.x = s0; lo.y = s1; lo.z = s2; lo.w = s3;
    hi.x = s4; hi.y = s5; hi.z = s6; hi.w = s7;
    float* pp = partials + (size_t)bid * H_DIM + t * 8;
    *(float4*)pp = lo;
    *(float4*)(pp + 4) = hi;
  } else if (bid < 1536) {
    const size_t base = (size_t)(bid - 1024) * 8192 + t * 8;
    float4 a[4], b[4];
#pragma unroll
    for (int j = 0; j < 4; ++j) {
      const float4* p = (const float4*)(wfh + base + j * 2048);
      a[j] = p[0];
      b[j] = p[1];
    }
#pragma unroll
    for (int j = 0; j < 4; ++j)
      *(uint4*)(wfhb + base + j * 2048) = packrow(a[j], b[j]);
  } else if (bid < 2048) {
    const int wave = t >> 6, lane = t & 63;
    const int h = (bid - 1536) * 4 + wave;  // 0..2047
    const float4* w = (const float4*)(Wfx + (size_t)h * D_IN);
    const float4* xv = (const float4*)x;
    float s = 0.f;
#pragma unroll
    for (int i = 0; i < 8; ++i) {
      int idx = i * 64 + lane;
      float4 av = w[idx], bv = xv[idx];
      s += av.x * bv.x + av.y * bv.y + av.z * bv.z + av.w * bv.w;
    }
#pragma unroll
    for (int off = 32; off > 0; off >>= 1) s += __shfl_xor(s, off);
    if (lane == 0) g[h] = s + bfx[h] + bfh[h];
  } else if (bid < 3584) {
    const int wave = t >> 6, lane = t & 63;
    const int row = (bid - 2048) * 4 + wave;  // 0..6143
    const float4* w = (const float4*)(Wix + (size_t)row * D_IN);
    const float4* xv = (const float4*)x;
    float s = 0.f;
#pragma unroll
    for (int i = 0; i < 8; ++i) {
      int idx = i * 64 + lane;
      float4 av = w[idx], bv = xv[idx];
      s += av.x * bv.x + av.y * bv.y + av.z * bv.z + av.w * bv.w;
    }
#pragma unroll
    for (int off = 32; off > 0; off >>= 1) s += __shfl_xor(s, off);
    if (lane == 0) ioux[row] = s + bix[row] + bih[row];
  } else {
    float4 z = {0.f, 0.f, 0.f, 0.f};
    ((float4*)hsum)[t * 2] = z;
    ((float4*)hsum)[t * 2 + 1] = z;
    ((float4*)accv)[t * 2] = z;
    ((float4*)accv)[t * 2 + 1] = z;
  }
}

// ---------------------------------------------------------------------------
// kG (320 blocks, 512 threads):
//  [0,64):   hsum reduction over partials (kred role; retires in ~5us).
//  [64,320): bf16 GEMM + sigmoid + weighted K-reduction.
//            Tile 256x128, BK=64, 8 waves (4m x 2n), LDS 96 KiB, 2-phase
//            dbuf, XCD-grouped swizzle (XCD x owns bm {2x,2x+1} x 16 bn ->
//            K-slices stay L2-resident per XCD).
// ---------------------------------------------------------------------------
#define BM 256
#define BN 128
#define BK 64

__global__ __launch_bounds__(512) void kG(
    const u16* __restrict__ chb, const float* __restrict__ cc,
    const u16* __restrict__ wfhb, const float* __restrict__ g,
    const float* __restrict__ partials, float* __restrict__ hsum,
    float* __restrict__ accv) {
  __shared__ u16 As[2][BM * BK];  // 64 KiB; row stride 64 u16 (128 B)
  __shared__ u16 Bs[2][BN * BK];  // 32 KiB

  const int bid = blockIdx.x;
  const int t = threadIdx.x;

  if (bid < 64) {
    // --- kred role: 512 threads = 256 cols x 2 row-halves ---
    const int c = (bid & 7) * 256 + (t & 255);
    const int p0 = (bid >> 3) * 128 + (t >> 8) * 64;
    float a0 = 0.f, a1 = 0.f, a2 = 0.f, a3 = 0.f;
    float a4 = 0.f, a5 = 0.f, a6 = 0.f, a7 = 0.f;
    for (int p = p0; p < p0 + 64; p += 8) {
      a0 += partials[(size_t)(p + 0) * H_DIM + c];
      a1 += partials[(size_t)(p + 1) * H_DIM + c];
      a2 += partials[(size_t)(p + 2) * H_DIM + c];
      a3 += partials[(size_t)(p + 3) * H_DIM + c];
      a4 += partials[(size_t)(p + 4) * H_DIM + c];
      a5 += partials[(size_t)(p + 5) * H_DIM + c];
      a6 += partials[(size_t)(p + 6) * H_DIM + c];
      a7 += partials[(size_t)(p + 7) * H_DIM + c];
    }
    float s = ((a0 + a1) + (a2 + a3)) + ((a4 + a5) + (a6 + a7));
    atomicAdd(hsum + c, s);
    return;
  }

  // --- GEMM role ---
  const int gb = bid - 64;                 // 0..255
  const int xcd = gb & 7;
  const int u = gb >> 3;                   // 0..31
  const int bm = (xcd << 1) | (u >> 4);    // 0..15
  const int bn = u & 15;                   // 0..15
  const int row0 = bm * BM;
  const int col0 = bn * BN;

  const int wave = t >> 6, lane = t & 63;
  const int lrow = lane & 15, lquad = lane >> 4;
  const int wm = wave >> 1, wn = wave & 1; // 4m x 2n -> per-wave 64x64 out

  f32x4 acc[4][4] = {};

  const int srow = lane >> 3;           // row within the 8-row group
  const int schunk = (lane & 7) ^ srow; // XOR-swizzled source chunk
  const u16* agbase = chb  + (size_t)(row0 + wave * 32 + srow) * H_DIM + schunk * 8;
  const u16* bgbase = wfhb + (size_t)(col0 + wave * 16 + srow) * H_DIM + schunk * 8;

#define STAGE(buf, kb)                                                        \
  do {                                                                        \
    _Pragma("unroll")                                                         \
    for (int i = 0; i < 4; ++i)                                               \
      __builtin_amdgcn_global_load_lds(                                       \
          (const __attribute__((address_space(1))) void*)(agbase + (size_t)i * 8 * H_DIM + (kb) * BK), \
          (__attribute__((address_space(3))) void*)(&As[buf][(wave * 32 + i * 8) * 64]), \
          16, 0, 0);                                                          \
    _Pragma("unroll")                                                         \
    for (int i = 0; i < 2; ++i)                                               \
      __builtin_amdgcn_global_load_lds(                                       \
          (const __attribute__((address_space(1))) void*)(bgbase + (size_t)i * 8 * H_DIM + (kb) * BK), \
          (__attribute__((address_space(3))) void*)(&Bs[buf][(wave * 16 + i * 8) * 64]), \
          16, 0, 0);                                                          \
  } while (0)

#define COMPUTE(buf)                                                          \
  do {                                                                        \
    _Pragma("unroll")                                                         \
    for (int step = 0; step < 2; ++step) {                                    \
      const int slot = ((step * 4 + lquad) ^ (lrow & 7)) * 8;                 \
      bf16x8 fa[4], fb[4];                                                    \
      _Pragma("unroll")                                                       \
      for (int i = 0; i < 4; ++i)                                             \
        fa[i] = *(const bf16x8*)(&As[buf][(wm * 64 + i * 16 + lrow) * 64 + slot]); \
      _Pragma("unroll")                                                       \
      for (int i = 0; i < 4; ++i)                                             \
        fb[i] = *(const bf16x8*)(&Bs[buf][(wn * 64 + i * 16 + lrow) * 64 + slot]); \
      _Pragma("unroll")                                                       \
      for (int mi = 0; mi < 4; ++mi)                                          \
        _Pragma("unroll")                                                     \
        for (int ni = 0; ni < 4; ++ni)                                        \
          acc[mi][ni] = __builtin_amdgcn_mfma_f32_16x16x32_bf16(              \
              fa[mi], fb[ni], acc[mi][ni], 0, 0, 0);                          \
    }                                                                         \
  } while (0)

  // prologue: tile 0 into buf 0
  STAGE(0, 0);
  __syncthreads();  // vmcnt(0) drain -> buf0 ready

  for (int kb = 0; kb < D_IN / BK - 1; ++kb) {
    const int cur = kb & 1;
    STAGE(cur ^ 1, kb + 1);  // issue next-tile loads BEFORE compute
    COMPUTE(cur);
    __syncthreads();         // drains vmcnt(0): buf^1 ready; reads of buf done
  }
  COMPUTE(1);  // tile 31

  // Epilogue. C/D layout: col = lane&15, row = (lane>>4)*4 + reg.
#pragma unroll
  for (int ni = 0; ni < 4; ++ni) {
    const int colg = col0 + wn * 64 + ni * 16 + lrow;
    const float gv = g[colg];
    float s = 0.f;
#pragma unroll
    for (int mi = 0; mi < 4; ++mi) {
      const int rowg = row0 + wm * 64 + mi * 16 + lquad * 4;
#pragma unroll
      for (int r = 0; r < 4; ++r) {
        float f = sigmoidf(gv + acc[mi][ni][r]);
        s += f * cc[(size_t)(rowg + r) * H_DIM + colg];
      }
    }
    s += __shfl_xor(s, 16);
    s += __shfl_xor(s, 32);
    if (lquad == 0) atomicAdd(accv + colg, s);
  }
#undef STAGE
#undef COMPUTE
}

// ---------------------------------------------------------------------------
// kmvF (512 blocks): fused iou-matvec + finalize, NO cross-block sync.
// Wave w of block b owns h = b*4+w and computes ALL THREE rows {h, H+h, 2H+h}
// of W_iou_h·hsum as interleaved dot products (same cached hsum vector), then
// lane 0 finalizes o/c/h for that h directly — replaces kmv + kfinal.
// ---------------------------------------------------------------------------
__global__ __launch_bounds__(256) void kmvF(const float* __restrict__ Wih,
                                            const float* __restrict__ hsum,
                                            const float* __restrict__ ioux,
                                            const float* __restrict__ accv,
                                            float* __restrict__ out) {
  const int wave = threadIdx.x >> 6, lane = threadIdx.x & 63;
  const int h = blockIdx.x * 4 + wave;  // 0..2047
  const float4* w0 = (const float4*)(Wih + (size_t)h * H_DIM);
  const float4* w1 = (const float4*)(Wih + (size_t)(H_DIM + h) * H_DIM);
  const float4* w2 = (const float4*)(Wih + (size_t)(2 * H_DIM + h) * H_DIM);
  const float4* hv = (const float4*)hsum;
  float s0 = 0.f, s1 = 0.f, s2 = 0.f;
#pragma unroll
  for (int i = 0; i < 8; ++i) {
    int idx = i * 64 + lane;
    float4 b = hv[idx];
    float4 a0 = w0[idx], a1 = w1[idx], a2 = w2[idx];
    s0 += a0.x * b.x + a0.y * b.y + a0.z * b.z + a0.w * b.w;
    s1 += a1.x * b.x + a1.y * b.y + a1.z * b.z + a1.w * b.w;
    s2 += a2.x * b.x + a2.y * b.y + a2.z * b.z + a2.w * b.w;
  }
#pragma unroll
  for (int off = 32; off > 0; off >>= 1) {
    s0 += __shfl_xor(s0, off);
    s1 += __shfl_xor(s1, off);
    s2 += __shfl_xor(s2, off);
  }
  if (lane == 0) {
    float i_ = sigmoidf(ioux[h] + s0);
    float o_ = sigmoidf(ioux[H_DIM + h] + s1);
    float u_ = tanhf(ioux[2 * H_DIM + h] + s2);
    float c_ = i_ * u_ + accv[h];
    float hh = o_ * tanhf(c_);
    out[h] = o_;
    out[H_DIM + h] = c_;
    out[2 * H_DIM + h] = hh;
  }
}

extern "C" void kernel_launch(void* const* d_in, const int* in_sizes, int n_in,
                              void* d_out, int out_size, void* d_ws, size_t ws_size,
                              hipStream_t stream) {
  const float* x   = (const float*)d_in[0];   // input [2048]
  const float* cc  = (const float*)d_in[1];   // children_c [4096,2048]
  const float* ch  = (const float*)d_in[2];   // children_h [4096,2048]
  const float* Wix = (const float*)d_in[3];   // W_iou_x [6144,2048]
  const float* bix = (const float*)d_in[4];   // b_iou_x [6144]
  const float* Wih = (const float*)d_in[5];   // W_iou_h [6144,2048]
  const float* bih = (const float*)d_in[6];   // b_iou_h [6144]
  const float* Wfx = (const float*)d_in[7];   // W_fx [2048,2048]
  const float* bfx = (const float*)d_in[8];   // b_fx [2048]
  const float* Wfh = (const float*)d_in[9];   // W_fh [2048,2048]
  const float* bfh = (const float*)d_in[10];  // b_fh [2048]

  float* ws   = (float*)d_ws;
  float* hsum = ws;                    // [2048]  (zeroed in k1; kG atomics)
  float* ioux = ws + 2048;             // [6144]  (Wix·x + bix + bih, by k1)
  float* g    = ws + 8192;             // [2048]
  float* accv = ws + 10240;            // [2048]  (zeroed in k1; kG atomics)
  float* partials = ws + 12288;        // [1024 * 2048]
  u16* chb  = (u16*)(ws + 12288 + 1024 * 2048);  // [4096*2048] bf16
  u16* wfhb = chb + (size_t)K_CH * H_DIM;        // [2048*2048] bf16
  float* out = (float*)d_out;

  k1<<<3585, 256, 0, stream>>>(ch, Wfh, Wfx, bfx, bfh, x, Wix, bix, bih,
                               partials, chb, wfhb, g, ioux, hsum, accv);
  kG<<<320, 512, 0, stream>>>(chb, cc, wfhb, g, partials, hsum, accv);
  kmvF<<<512, 256, 0, stream>>>(Wih, hsum, ioux, accv, out);
}